// Round 8
// baseline (1963.816 us; speedup 1.0000x reference)
//
#include <hip/hip_runtime.h>
#include <cstdint>
#include <cstddef>

#define TAU_D 2.053748910631823
#define M_DIM 8192
#define N_DIM 4096
#define K_DIM 4096
#define NT32  (K_DIM / 32)     // 128 K-tiles of BK=32

typedef float f32x4 __attribute__((ext_vector_type(4)));
typedef short bf16x8 __attribute__((ext_vector_type(8)));

typedef __attribute__((address_space(1))) void gvoid_t;
typedef __attribute__((address_space(3))) void lvoid_t;

__device__ __forceinline__ void gload_lds16(const void* g, void* l) {
    __builtin_amdgcn_global_load_lds((const gvoid_t*)g, (lvoid_t*)l, 16, 0, 0);
}

__device__ __forceinline__ unsigned int pack2bf(float lo, float hi) {
    unsigned int ul = __float_as_uint(lo);
    unsigned int uh = __float_as_uint(hi);
    ul = (ul + 0x7FFFu + ((ul >> 16) & 1u)) >> 16;
    uh = (uh + 0x7FFFu + ((uh >> 16) & 1u)) >> 16;
    return ul | (uh << 16);
}

// fp32 -> bf16 (RNE), vectorized: 16B in / 8B out per thread per iter.
__global__ void cvt_f32_to_bf16(const float4* __restrict__ in,
                                uint2* __restrict__ out, int n4) {
    int i = blockIdx.x * blockDim.x + threadIdx.x;
    const int stride = gridDim.x * blockDim.x;
    for (; i < n4; i += stride) {
        float4 a = in[i];
        uint2 o;
        o.x = pack2bf(a.x, a.y);
        o.y = pack2bf(a.z, a.w);
        out[i] = o;
    }
}

// ============================================================================
// 256x256 tile, BK=32, 8 waves (2Mx4N), 512 thr, 2 LDS buffers = 64KB
// -> 2 BLOCKS/CU (launch_bounds(512,4)): cross-block overlap covers the
// boundary drain (m114 mechanism) that stalled the 1-block/CU designs.
// Per tile: 2 phases x 16 MFMA; stage A(T+1)@ph1 (2 gloads), B(T+1)@ph2;
// boundary = full drain (per-wave vmcnt ledger proves counted wait can't be
// below drain when the whole next tile stages within the current tile).
// Slot-rotation swizzle kept (conflicts ~2.6% of cycles - non-issue).
// XCD map: 64 concurrent blocks/XCD form a compact 8x8 tile cluster.
// Mask epilogue replicates numpy fp32 sgemm bit-exactly (verified r3-r7).
// ============================================================================
__global__ __launch_bounds__(512, 4) void gemm_masked8(
    const unsigned short* __restrict__ Ab,   // x bf16 [M][K]
    const unsigned short* __restrict__ Bb,   // W bf16 [N][K]
    const float* __restrict__ X,             // x fp32 (mask)
    const float* __restrict__ Wt,            // W fp32 (mask)
    const float* __restrict__ bias,
    float* __restrict__ out)
{
    __shared__ __align__(16) char lds[65536];   // 2 x (A 16KB + B 16KB)

    const int tid  = threadIdx.x;
    const int wave = tid >> 6;
    const int lane = tid & 63;
    const int lr = lane & 15;
    const int lq = lane >> 4;
    const int wm = wave >> 2;    // 0..1 : row half (128 rows)
    const int wn = wave & 3;     // 0..3 : 64-col slice

    // XCD cluster map: 512 blocks, 2 blocks/CU -> all concurrent.
    // XCD k = flat&7 gets slots s = flat>>3 (64) -> 8 tile-rows x 8 tile-cols.
    const int flat = blockIdx.x;
    const int xcd  = flat & 7;
    const int s    = flat >> 3;            // 0..63
    const int trow = ((xcd >> 1) << 3) + (s >> 3);   // 0..31
    const int tcol = ((xcd & 1) << 3) + (s & 7);     // 0..15
    const int rowBase = trow * 256;
    const int colBase = tcol * 256;

    f32x4 acc[8][4];
    #pragma unroll
    for (int i = 0; i < 8; ++i)
        #pragma unroll
        for (int n = 0; n < 4; ++n)
            acc[i][n] = (f32x4){0.f, 0.f, 0.f, 0.f};

    // ---- staging (linear LDS dest; source column pre-rotated, rule 21) ----
    // gload instr i of an operand: flat byte = opBase + i*8192 + tid*16
    //   -> row = i*128 + (tid>>2), phys 16B-slot p = tid&3.
    // slot map: phys = (logical + (row>>1)) & 3
    //   -> logical = ((tid&3) - ((tid>>3)&3)) & 3.
    const int srow = tid >> 2;                                   // 0..127
    const int slog = ((tid & 3) - ((tid >> 3) & 3)) & 3;
    const unsigned short* aSrc =
        Ab + (size_t)(rowBase + srow) * K_DIM + slog * 8;
    const unsigned short* bSrc =
        Bb + (size_t)(colBase + srow) * K_DIM + slog * 8;

    // ---- ds_read offsets (buffer-relative, K-tile independent) ----
    // A frag m: row = wm*128 + m*16 + lr; phys slot = (lq + (lr>>1)) & 3.
    const unsigned skrot = (unsigned)((lq + (lr >> 1)) & 3) * 16;
    const unsigned offA0 = (unsigned)(wm * 128 + lr) * 64 + skrot;
    const unsigned offB0 = 16384u + (unsigned)(wn * 64 + lr) * 64 + skrot;

    // ---- prologue: stage K-tile 0 into buffer 0 ----
    #pragma unroll
    for (int i = 0; i < 2; ++i)
        gload_lds16(aSrc + (size_t)i * 128 * K_DIM, lds + i * 8192 + wave * 1024);
    #pragma unroll
    for (int i = 0; i < 2; ++i)
        gload_lds16(bSrc + (size_t)i * 128 * K_DIM, lds + 16384 + i * 8192 + wave * 1024);
    __syncthreads();

    for (int T = 0; T < NT32; ++T) {
        const bool st = (T + 1 < NT32);
        const unsigned cb = (unsigned)(T & 1) << 15;   // 0 / 32768
        const unsigned ob = cb ^ 32768u;
        const char* L = lds + cb;
        const unsigned short* aS = aSrc + (size_t)(T + 1) * 32;
        const unsigned short* bS = bSrc + (size_t)(T + 1) * 32;

        bf16x8 af[4], bq[4];

        // ---------- phase 1: m0-3 x n0-3; stage A(T+1) ----------
        #pragma unroll
        for (int m = 0; m < 4; ++m)
            af[m] = *(const bf16x8*)(L + offA0 + m * 1024);
        #pragma unroll
        for (int n = 0; n < 4; ++n)
            bq[n] = *(const bf16x8*)(L + offB0 + n * 1024);
        if (st) {
            #pragma unroll
            for (int i = 0; i < 2; ++i)
                gload_lds16(aS + (size_t)i * 128 * K_DIM,
                            lds + ob + i * 8192 + wave * 1024);
        }
        __builtin_amdgcn_s_barrier();
        __builtin_amdgcn_sched_barrier(0);
        __builtin_amdgcn_s_setprio(1);
        #pragma unroll
        for (int m = 0; m < 4; ++m)
            #pragma unroll
            for (int n = 0; n < 4; ++n)
                acc[m][n] = __builtin_amdgcn_mfma_f32_16x16x32_bf16(
                    af[m], bq[n], acc[m][n], 0, 0, 0);
        __builtin_amdgcn_s_setprio(0);
        __builtin_amdgcn_s_barrier();
        __builtin_amdgcn_sched_barrier(0);

        // ---------- phase 2: m4-7 x n0-3; stage B(T+1) ----------
        #pragma unroll
        for (int m = 0; m < 4; ++m)
            af[m] = *(const bf16x8*)(L + offA0 + (4 + m) * 1024);
        if (st) {
            #pragma unroll
            for (int i = 0; i < 2; ++i)
                gload_lds16(bS + (size_t)i * 128 * K_DIM,
                            lds + ob + 16384 + i * 8192 + wave * 1024);
        }
        __builtin_amdgcn_s_barrier();
        __builtin_amdgcn_sched_barrier(0);
        __builtin_amdgcn_s_setprio(1);
        #pragma unroll
        for (int m = 0; m < 4; ++m)
            #pragma unroll
            for (int n = 0; n < 4; ++n)
                acc[4 + m][n] = __builtin_amdgcn_mfma_f32_16x16x32_bf16(
                    af[m], bq[n], acc[4 + m][n], 0, 0, 0);
        __builtin_amdgcn_s_setprio(0);

        // ---------- boundary: full drain; the co-resident block covers it --
        __syncthreads();
    }

    // ---- epilogue: bit-exact fp32 mask + bias + store (verified r3-r7) ----
    float* x0s = (float*)(lds);            // [256][16] f32, 16KB
    float* w0s = (float*)(lds + 16384);    // [256][16] f32
    #pragma unroll
    for (int i = 0; i < 2; ++i) {
        int idx = tid + i * 512;           // 1024 float4 slots
        int r = idx >> 2, qq = (idx & 3) << 2;
        *(f32x4*)(x0s + r * 16 + qq) =
            *(const f32x4*)(X + (size_t)(rowBase + r) * K_DIM + qq);
        *(f32x4*)(w0s + r * 16 + qq) =
            *(const f32x4*)(Wt + (size_t)(colBase + r) * K_DIM + qq);
    }
    __syncthreads();

    const float TAU32 = (float)TAU_D;

    // n in adjacent pairs: both 64B halves of each 128B output line stored
    // back-to-back (write-amplification fix, verified r6/r7).
    #pragma unroll
    for (int np = 0; np < 4; np += 2) {
        float wv[2][16];
        float bv[2];
        #pragma unroll
        for (int e = 0; e < 2; ++e) {
            const int c = wn * 64 + (np + e) * 16 + lr;
            #pragma unroll
            for (int q = 0; q < 4; ++q)
                *(f32x4*)&wv[e][q * 4] = *(const f32x4*)(w0s + c * 16 + q * 4);
            bv[e] = bias[colBase + c];
        }
        #pragma unroll
        for (int mi = 0; mi < 8; ++mi) {
            #pragma unroll
            for (int j = 0; j < 4; ++j) {
                const int rw = wm * 128 + mi * 16 + lq * 4 + j;
                float xv[16];
                #pragma unroll
                for (int q = 0; q < 4; ++q)
                    *(f32x4*)&xv[q * 4] = *(const f32x4*)(x0s + rw * 16 + q * 4);
                const size_t orow = (size_t)(rowBase + rw) * N_DIM + colBase;
                #pragma unroll
                for (int e = 0; e < 2; ++e) {
                    const int n = np + e;
                    // Replicate BLAS sgemm: single-acc fma chain, k ascending.
                    float y1 = 0.f, s2 = 0.f;
                    #pragma unroll
                    for (int k = 0; k < 16; ++k) {
                        float xk = xv[k], wk = wv[e][k];
                        float xx = xk * xk, ww = wk * wk;
                        y1 = fmaf(xk, wk, y1);
                        s2 = fmaf(xx, ww, s2);
                    }
                    float t = fabsf(y1) / sqrtf(s2 * 0.0625f);
                    float v = (t < TAU32) ? 0.0f : (acc[mi][n][j] + bv[e]);
                    out[orow + wn * 64 + n * 16 + lr] = v;
                }
            }
        }
    }
}

// ============================================================================
// Fallback (no workspace): round-3 verified 128x128 kernel, reg-staged cvt.
// ============================================================================
__global__ __launch_bounds__(256, 2) void gemm_masked_fb(
    const float* __restrict__ X, const float* __restrict__ Wt,
    const float* __restrict__ bias, float* __restrict__ out)
{
    __shared__ __align__(16) unsigned short As[128 * 32];
    __shared__ __align__(16) unsigned short Bs[128 * 32];

    const int tid  = threadIdx.x;
    const int wave = tid >> 6;
    const int lane = tid & 63;
    const int rowBase = blockIdx.y * 128;
    const int colBase = blockIdx.x * 128;
    const int wr = wave >> 1;
    const int wc = wave & 1;
    const int lr = lane & 15;
    const int lq = lane >> 4;

    f32x4 acc[4][4];
    #pragma unroll
    for (int m = 0; m < 4; ++m)
        #pragma unroll
        for (int n = 0; n < 4; ++n)
            acc[m][n] = (f32x4){0.f, 0.f, 0.f, 0.f};

    const int srow = tid >> 2;
    const int scol = (tid & 3) * 8;
    const float* afp = X  + (size_t)(rowBase + srow) * K_DIM + scol;
    const float* bfp = Wt + (size_t)(colBase + srow) * K_DIM + scol;

    for (int kt = 0; kt < K_DIM; kt += 32) {
        #pragma unroll
        for (int issue = 0; issue < 2; ++issue) {
            const float* sa = afp + (size_t)issue * 64 * K_DIM;
            const float* sb = bfp + (size_t)issue * 64 * K_DIM;
            float4 a0 = *(const float4*)(sa);
            float4 a1 = *(const float4*)(sa + 4);
            float4 b0 = *(const float4*)(sb);
            float4 b1 = *(const float4*)(sb + 4);
            uint4 pa, pb;
            pa.x = pack2bf(a0.x, a0.y); pa.y = pack2bf(a0.z, a0.w);
            pa.z = pack2bf(a1.x, a1.y); pa.w = pack2bf(a1.z, a1.w);
            pb.x = pack2bf(b0.x, b0.y); pb.y = pack2bf(b0.z, b0.w);
            pb.z = pack2bf(b1.x, b1.y); pb.w = pack2bf(b1.z, b1.w);
            *(uint4*)((char*)As + issue * 4096 + tid * 16) = pa;
            *(uint4*)((char*)Bs + issue * 4096 + tid * 16) = pb;
        }
        afp += 32; bfp += 32;
        __syncthreads();

        bf16x8 af[4], bq[4];
        #pragma unroll
        for (int m = 0; m < 4; ++m)
            af[m] = *(const bf16x8*)(As + (wr * 64 + m * 16 + lr) * 32 + lq * 8);
        #pragma unroll
        for (int n = 0; n < 4; ++n)
            bq[n] = *(const bf16x8*)(Bs + (wc * 64 + n * 16 + lr) * 32 + lq * 8);
        #pragma unroll
        for (int m = 0; m < 4; ++m)
            #pragma unroll
            for (int n = 0; n < 4; ++n)
                acc[m][n] = __builtin_amdgcn_mfma_f32_16x16x32_bf16(
                    af[m], bq[n], acc[m][n], 0, 0, 0);
        __syncthreads();
    }

    float* x0s = (float*)As;
    float* w0s = (float*)Bs;
    #pragma unroll
    for (int i = 0; i < 2; ++i) {
        int idx = tid + i * 256;
        int r = idx >> 2, q = (idx & 3) * 4;
        *(float4*)(x0s + r * 16 + q) =
            *(const float4*)(X + (size_t)(rowBase + r) * K_DIM + q);
        *(float4*)(w0s + r * 16 + q) =
            *(const float4*)(Wt + (size_t)(colBase + r) * K_DIM + q);
    }
    __syncthreads();

    const float TAU32 = (float)TAU_D;
    float wv[4][16];
    float bv[4];
    #pragma unroll
    for (int n = 0; n < 4; ++n) {
        int c = wc * 64 + n * 16 + lr;
        #pragma unroll
        for (int q = 0; q < 4; ++q)
            *(f32x4*)&wv[n][q * 4] = *(const f32x4*)(w0s + c * 16 + q * 4);
        bv[n] = bias[colBase + c];
    }

    #pragma unroll
    for (int m = 0; m < 4; ++m) {
        #pragma unroll
        for (int j = 0; j < 4; ++j) {
            const int r = wr * 64 + m * 16 + lq * 4 + j;
            float xv[16];
            #pragma unroll
            for (int q = 0; q < 4; ++q)
                *(f32x4*)&xv[q * 4] = *(const f32x4*)(x0s + r * 16 + q * 4);
            const size_t orow = (size_t)(rowBase + r) * N_DIM + colBase;
            #pragma unroll
            for (int n = 0; n < 4; ++n) {
                float y1 = 0.f, s2 = 0.f;
                #pragma unroll
                for (int k = 0; k < 16; ++k) {
                    float xk = xv[k];
                    float wk = wv[n][k];
                    float xx = xk * xk;
                    float ww = wk * wk;
                    y1 = fmaf(xk, wk, y1);
                    s2 = fmaf(xx, ww, s2);
                }
                float t = fabsf(y1) / sqrtf(s2 * 0.0625f);
                float v = (t < TAU32) ? 0.0f : (acc[m][n][j] + bv[n]);
                out[orow + wc * 64 + n * 16 + lr] = v;
            }
        }
    }
}

extern "C" void kernel_launch(void* const* d_in, const int* in_sizes, int n_in,
                              void* d_out, int out_size, void* d_ws, size_t ws_size,
                              hipStream_t stream) {
    const float* x    = (const float*)d_in[0];
    const float* W    = (const float*)d_in[1];
    const float* bias = (const float*)d_in[2];
    float* out = (float*)d_out;

    const size_t needA = (size_t)M_DIM * K_DIM * 2;   // 64 MB
    const size_t needB = (size_t)N_DIM * K_DIM * 2;   // 32 MB

    if (ws_size >= needA + needB) {
        unsigned short* xb = (unsigned short*)d_ws;
        unsigned short* wb = (unsigned short*)((char*)d_ws + needA);
        cvt_f32_to_bf16<<<2048, 256, 0, stream>>>(
            (const float4*)x, (uint2*)xb, (M_DIM * K_DIM) / 4);
        cvt_f32_to_bf16<<<2048, 256, 0, stream>>>(
            (const float4*)W, (uint2*)wb, (N_DIM * K_DIM) / 4);
        dim3 grid((M_DIM / 256) * (N_DIM / 256));     // 512 blocks, 1-D
        gemm_masked8<<<grid, 512, 0, stream>>>(xb, wb, x, W, bias, out);
    } else {
        dim3 grid(N_DIM / 128, M_DIM / 128);
        gemm_masked_fb<<<grid, 256, 0, stream>>>(x, W, bias, out);
    }
}

// Round 9
// 353.399 us; speedup vs baseline: 5.5569x; 5.5569x over previous
//
#include <hip/hip_runtime.h>
#include <cstdint>
#include <cstddef>

#define TAU_D 2.053748910631823
#define M_DIM 8192
#define N_DIM 4096
#define K_DIM 4096
#define NT64  (K_DIM / 64)     // 64 K-tiles of BK=64

typedef float f32x4  __attribute__((ext_vector_type(4)));
typedef float f32x16 __attribute__((ext_vector_type(16)));
typedef short bf16x8 __attribute__((ext_vector_type(8)));

typedef __attribute__((address_space(1))) void gvoid_t;
typedef __attribute__((address_space(3))) void lvoid_t;

__device__ __forceinline__ void gload_lds16(const void* g, void* l) {
    __builtin_amdgcn_global_load_lds((const gvoid_t*)g, (lvoid_t*)l, 16, 0, 0);
}

__device__ __forceinline__ unsigned int pack2bf(float lo, float hi) {
    unsigned int ul = __float_as_uint(lo);
    unsigned int uh = __float_as_uint(hi);
    ul = (ul + 0x7FFFu + ((ul >> 16) & 1u)) >> 16;
    uh = (uh + 0x7FFFu + ((uh >> 16) & 1u)) >> 16;
    return ul | (uh << 16);
}

// fp32 -> bf16 (RNE), vectorized: 16B in / 8B out per thread per iter.
__global__ void cvt_f32_to_bf16(const float4* __restrict__ in,
                                uint2* __restrict__ out, int n4) {
    int i = blockIdx.x * blockDim.x + threadIdx.x;
    const int stride = gridDim.x * blockDim.x;
    for (; i < n4; i += stride) {
        float4 a = in[i];
        uint2 o;
        o.x = pack2bf(a.x, a.y);
        o.y = pack2bf(a.z, a.w);
        out[i] = o;
    }
}

// ============================================================================
// r6 structure (verified 312us) with 32x32x16 MFMA (+15-20% matrix ceiling,
// half the MFMA instruction count at identical LDS traffic).
// 256x256 tile, BK=64, 8 waves (2Mx4N), 512 thr, 2 LDS buffers (128KB),
// 1 block/CU (launch_bounds(512,2) -- r8 proved 2 blocks/CU reg-infeasible).
// 4 phases/K-tile = (k-half x m-half), 8 MFMA each; B frags reused across
// m-phases; stage A(T+1)@ph1, B(T+1)@ph2; full-drain boundary.
// T2 XOR-swizzle (verified r6): phys 16B-slot = logical ^ (row&7); linear LDS
// dest + pre-swizzled GLOBAL source + swizzled ds_read.
// XCD map (verified r6, FETCH 208MB): 32 concurrent blocks/XCD = 8x4 cluster.
// Mask epilogue replicates numpy fp32 sgemm bit-exactly (verified r3-r8).
// 32x32 C/D layout (HW-verified m101): col=lane&31, row=(j&3)+8*(j>>2)+4*(lane>>5).
// ============================================================================
__global__ __launch_bounds__(512, 2) void gemm_masked8(
    const unsigned short* __restrict__ Ab,   // x bf16 [M][K]
    const unsigned short* __restrict__ Bb,   // W bf16 [N][K]
    const float* __restrict__ X,             // x fp32 (mask)
    const float* __restrict__ Wt,            // W fp32 (mask)
    const float* __restrict__ bias,
    float* __restrict__ out)
{
    __shared__ __align__(16) char lds[131072];   // 2 x (A 32KB + B 32KB)

    const int tid  = threadIdx.x;
    const int wave = tid >> 6;
    const int lane = tid & 63;
    const int lc = lane & 31;    // row/col within 32-tile
    const int lh = lane >> 5;    // k-group (0/1)
    const int wm = wave >> 2;    // 0..1 : row half (128 rows)
    const int wn = wave & 3;     // 0..3 : 64-col slice

    // Concurrency-aware XCD cluster map (verified r6).
    const int flat = blockIdx.x;
    const int xcd  = flat & 7;
    const int s    = flat >> 3;            // 0..63
    const int rnd  = s >> 5;               // 0..1
    const int jj   = s & 31;               // 0..31
    const int trow = rnd * 16 + ((xcd >> 2) << 3) + (jj >> 2);   // 0..31
    const int tcol = ((xcd & 3) << 2) + (jj & 3);                // 0..15
    const int rowBase = trow * 256;
    const int colBase = tcol * 256;

    f32x16 acc[4][2];
    #pragma unroll
    for (int m = 0; m < 4; ++m)
        #pragma unroll
        for (int n = 0; n < 2; ++n)
            acc[m][n] = (f32x16)(0.f);

    // ---- staging (verified r6): linear LDS dest; global col pre-swizzled --
    // gload instr i: flat byte = opBase + i*8192 + tid*16
    //   -> row = i*64 + (tid>>3), phys 16B-slot = tid&7,
    //      logical slot fetched = (tid&7) ^ ((tid>>3)&7).
    const int srow  = tid >> 3;                       // 0..63
    const int sslot = (tid & 7) ^ (srow & 7);
    const unsigned short* aSrc =
        Ab + (size_t)(rowBase + srow) * K_DIM + sslot * 8;
    const unsigned short* bSrc =
        Bb + (size_t)(colBase + srow) * K_DIM + sslot * 8;

    // ---- ds_read frag offsets (32x32x16 A/B layout) ----
    // A m-tile, kstep ks: row = wm*128 + m*32 + lc ; k = ks*16 + lh*8 + e
    //   -> logical slot = ks*2 + lh ; phys = slot ^ (row&7) = slot ^ (lc&7).
    unsigned sk[4];
    #pragma unroll
    for (int ks = 0; ks < 4; ++ks)
        sk[ks] = (unsigned)((ks * 2 + lh) ^ (lc & 7)) * 16;
    const unsigned baseA = (unsigned)(wm * 128 + lc) * 128;           // + m*4096
    const unsigned baseB = 32768u + (unsigned)(wn * 64 + lc) * 128;   // + n*4096

    // ---- prologue: stage K-tile 0 into buffer 0 ----
    #pragma unroll
    for (int i = 0; i < 4; ++i)
        gload_lds16(aSrc + (size_t)i * 64 * K_DIM,
                    lds + i * 8192 + wave * 1024);
    #pragma unroll
    for (int i = 0; i < 4; ++i)
        gload_lds16(bSrc + (size_t)i * 64 * K_DIM,
                    lds + 32768 + i * 8192 + wave * 1024);
    __syncthreads();

    for (int T = 0; T < NT64; ++T) {
        const bool st = (T + 1 < NT64);
        const unsigned cb = (unsigned)(T & 1) << 16;   // 0 / 65536
        const unsigned ob = cb ^ 65536u;
        const char* L = lds + cb;
        const unsigned short* aS = aSrc + (size_t)(T + 1) * 64;
        const unsigned short* bS = bSrc + (size_t)(T + 1) * 64;

        bf16x8 aF[2][2], bF[2][2];   // [tile-in-pair][ks-in-pair]

        // ---------- phase 1: k-half0, m-half0; stage A(T+1) ----------
        #pragma unroll
        for (int mm = 0; mm < 2; ++mm)
            #pragma unroll
            for (int kk = 0; kk < 2; ++kk)
                aF[mm][kk] = *(const bf16x8*)(L + baseA + mm * 4096 + sk[kk]);
        #pragma unroll
        for (int nn = 0; nn < 2; ++nn)
            #pragma unroll
            for (int kk = 0; kk < 2; ++kk)
                bF[nn][kk] = *(const bf16x8*)(L + baseB + nn * 4096 + sk[kk]);
        if (st) {
            #pragma unroll
            for (int i = 0; i < 4; ++i)
                gload_lds16(aS + (size_t)i * 64 * K_DIM,
                            lds + ob + i * 8192 + wave * 1024);
        }
        __builtin_amdgcn_s_barrier();
        __builtin_amdgcn_sched_barrier(0);
        __builtin_amdgcn_s_setprio(1);
        #pragma unroll
        for (int mm = 0; mm < 2; ++mm)
            #pragma unroll
            for (int nn = 0; nn < 2; ++nn)
                #pragma unroll
                for (int kk = 0; kk < 2; ++kk)
                    acc[mm][nn] = __builtin_amdgcn_mfma_f32_32x32x16_bf16(
                        aF[mm][kk], bF[nn][kk], acc[mm][nn], 0, 0, 0);
        __builtin_amdgcn_s_setprio(0);
        __builtin_amdgcn_s_barrier();
        __builtin_amdgcn_sched_barrier(0);

        // ---------- phase 2: k-half0, m-half1; stage B(T+1) ----------
        #pragma unroll
        for (int mm = 0; mm < 2; ++mm)
            #pragma unroll
            for (int kk = 0; kk < 2; ++kk)
                aF[mm][kk] = *(const bf16x8*)(L + baseA + (2 + mm) * 4096 + sk[kk]);
        if (st) {
            #pragma unroll
            for (int i = 0; i < 4; ++i)
                gload_lds16(bS + (size_t)i * 64 * K_DIM,
                            lds + ob + 32768 + i * 8192 + wave * 1024);
        }
        __builtin_amdgcn_s_barrier();
        __builtin_amdgcn_sched_barrier(0);
        __builtin_amdgcn_s_setprio(1);
        #pragma unroll
        for (int mm = 0; mm < 2; ++mm)
            #pragma unroll
            for (int nn = 0; nn < 2; ++nn)
                #pragma unroll
                for (int kk = 0; kk < 2; ++kk)
                    acc[2 + mm][nn] = __builtin_amdgcn_mfma_f32_32x32x16_bf16(
                        aF[mm][kk], bF[nn][kk], acc[2 + mm][nn], 0, 0, 0);
        __builtin_amdgcn_s_setprio(0);
        __builtin_amdgcn_s_barrier();
        __builtin_amdgcn_sched_barrier(0);

        // ---------- phase 3: k-half1, m-half0 ----------
        #pragma unroll
        for (int mm = 0; mm < 2; ++mm)
            #pragma unroll
            for (int kk = 0; kk < 2; ++kk)
                aF[mm][kk] = *(const bf16x8*)(L + baseA + mm * 4096 + sk[2 + kk]);
        #pragma unroll
        for (int nn = 0; nn < 2; ++nn)
            #pragma unroll
            for (int kk = 0; kk < 2; ++kk)
                bF[nn][kk] = *(const bf16x8*)(L + baseB + nn * 4096 + sk[2 + kk]);
        __builtin_amdgcn_s_barrier();
        __builtin_amdgcn_sched_barrier(0);
        __builtin_amdgcn_s_setprio(1);
        #pragma unroll
        for (int mm = 0; mm < 2; ++mm)
            #pragma unroll
            for (int nn = 0; nn < 2; ++nn)
                #pragma unroll
                for (int kk = 0; kk < 2; ++kk)
                    acc[mm][nn] = __builtin_amdgcn_mfma_f32_32x32x16_bf16(
                        aF[mm][kk], bF[nn][kk], acc[mm][nn], 0, 0, 0);
        __builtin_amdgcn_s_setprio(0);
        __builtin_amdgcn_s_barrier();
        __builtin_amdgcn_sched_barrier(0);

        // ---------- phase 4: k-half1, m-half1 ----------
        #pragma unroll
        for (int mm = 0; mm < 2; ++mm)
            #pragma unroll
            for (int kk = 0; kk < 2; ++kk)
                aF[mm][kk] = *(const bf16x8*)(L + baseA + (2 + mm) * 4096 + sk[2 + kk]);
        __builtin_amdgcn_s_barrier();
        __builtin_amdgcn_sched_barrier(0);
        __builtin_amdgcn_s_setprio(1);
        #pragma unroll
        for (int mm = 0; mm < 2; ++mm)
            #pragma unroll
            for (int nn = 0; nn < 2; ++nn)
                #pragma unroll
                for (int kk = 0; kk < 2; ++kk)
                    acc[2 + mm][nn] = __builtin_amdgcn_mfma_f32_32x32x16_bf16(
                        aF[mm][kk], bF[nn][kk], acc[2 + mm][nn], 0, 0, 0);
        __builtin_amdgcn_s_setprio(0);

        // ---------- boundary: full drain (loads aged 2-3 phases) ----------
        __syncthreads();
    }

    // ---- epilogue: bit-exact fp32 mask + bias + store (verified r3-r8) ----
    float* x0s = (float*)(lds);            // [256][16] f32, 16KB
    float* w0s = (float*)(lds + 16384);    // [256][16] f32
    #pragma unroll
    for (int i = 0; i < 2; ++i) {
        int idx = tid + i * 512;           // 1024 float4 slots
        int r = idx >> 2, qq = (idx & 3) << 2;
        *(f32x4*)(x0s + r * 16 + qq) =
            *(const f32x4*)(X + (size_t)(rowBase + r) * K_DIM + qq);
        *(f32x4*)(w0s + r * 16 + qq) =
            *(const f32x4*)(Wt + (size_t)(colBase + r) * K_DIM + qq);
    }
    __syncthreads();

    const float TAU32 = (float)TAU_D;

    // wv for both n-tiles (cols fixed per lane), then sweep (m, j) rows;
    // per (m,j) both n stores complete their 128B lines in single wave ops.
    float wv[2][16];
    float bv[2];
    #pragma unroll
    for (int n = 0; n < 2; ++n) {
        const int c = wn * 64 + n * 32 + lc;
        #pragma unroll
        for (int q = 0; q < 4; ++q)
            *(f32x4*)&wv[n][q * 4] = *(const f32x4*)(w0s + c * 16 + q * 4);
        bv[n] = bias[colBase + c];
    }

    #pragma unroll
    for (int m = 0; m < 4; ++m) {
        #pragma unroll
        for (int j = 0; j < 16; ++j) {
            const int rw = wm * 128 + m * 32 + (j & 3) + 8 * (j >> 2) + 4 * lh;
            float xv[16];
            #pragma unroll
            for (int q = 0; q < 4; ++q)
                *(f32x4*)&xv[q * 4] = *(const f32x4*)(x0s + rw * 16 + q * 4);
            const size_t orow = (size_t)(rowBase + rw) * N_DIM + colBase;
            #pragma unroll
            for (int n = 0; n < 2; ++n) {
                // Replicate BLAS sgemm: single-acc fma chain, k ascending.
                float y1 = 0.f, s2 = 0.f;
                #pragma unroll
                for (int k = 0; k < 16; ++k) {
                    float xk = xv[k], wk = wv[n][k];
                    float xx = xk * xk, ww = wk * wk;
                    y1 = fmaf(xk, wk, y1);
                    s2 = fmaf(xx, ww, s2);
                }
                float t = fabsf(y1) / sqrtf(s2 * 0.0625f);
                float v = (t < TAU32) ? 0.0f : (acc[m][n][j] + bv[n]);
                out[orow + wn * 64 + n * 32 + lc] = v;
            }
        }
    }
}

// ============================================================================
// Fallback (no workspace): round-3 verified 128x128 kernel, reg-staged cvt.
// ============================================================================
__global__ __launch_bounds__(256, 2) void gemm_masked_fb(
    const float* __restrict__ X, const float* __restrict__ Wt,
    const float* __restrict__ bias, float* __restrict__ out)
{
    __shared__ __align__(16) unsigned short As[128 * 32];
    __shared__ __align__(16) unsigned short Bs[128 * 32];

    const int tid  = threadIdx.x;
    const int wave = tid >> 6;
    const int lane = tid & 63;
    const int rowBase = blockIdx.y * 128;
    const int colBase = blockIdx.x * 128;
    const int wr = wave >> 1;
    const int wc = wave & 1;
    const int lr = lane & 15;
    const int lq = lane >> 4;

    f32x4 acc[4][4];
    #pragma unroll
    for (int m = 0; m < 4; ++m)
        #pragma unroll
        for (int n = 0; n < 4; ++n)
            acc[m][n] = (f32x4){0.f, 0.f, 0.f, 0.f};

    const int srow = tid >> 2;
    const int scol = (tid & 3) * 8;
    const float* afp = X  + (size_t)(rowBase + srow) * K_DIM + scol;
    const float* bfp = Wt + (size_t)(colBase + srow) * K_DIM + scol;

    for (int kt = 0; kt < K_DIM; kt += 32) {
        #pragma unroll
        for (int issue = 0; issue < 2; ++issue) {
            const float* sa = afp + (size_t)issue * 64 * K_DIM;
            const float* sb = bfp + (size_t)issue * 64 * K_DIM;
            float4 a0 = *(const float4*)(sa);
            float4 a1 = *(const float4*)(sa + 4);
            float4 b0 = *(const float4*)(sb);
            float4 b1 = *(const float4*)(sb + 4);
            uint4 pa, pb;
            pa.x = pack2bf(a0.x, a0.y); pa.y = pack2bf(a0.z, a0.w);
            pa.z = pack2bf(a1.x, a1.y); pa.w = pack2bf(a1.z, a1.w);
            pb.x = pack2bf(b0.x, b0.y); pb.y = pack2bf(b0.z, b0.w);
            pb.z = pack2bf(b1.x, b1.y); pb.w = pack2bf(b1.z, b1.w);
            *(uint4*)((char*)As + issue * 4096 + tid * 16) = pa;
            *(uint4*)((char*)Bs + issue * 4096 + tid * 16) = pb;
        }
        afp += 32; bfp += 32;
        __syncthreads();

        bf16x8 af[4], bq[4];
        #pragma unroll
        for (int m = 0; m < 4; ++m)
            af[m] = *(const bf16x8*)(As + (wr * 64 + m * 16 + lr) * 32 + lq * 8);
        #pragma unroll
        for (int n = 0; n < 4; ++n)
            bq[n] = *(const bf16x8*)(Bs + (wc * 64 + n * 16 + lr) * 32 + lq * 8);
        #pragma unroll
        for (int m = 0; m < 4; ++m)
            #pragma unroll
            for (int n = 0; n < 4; ++n)
                acc[m][n] = __builtin_amdgcn_mfma_f32_16x16x32_bf16(
                    af[m], bq[n], acc[m][n], 0, 0, 0);
        __syncthreads();
    }

    float* x0s = (float*)As;
    float* w0s = (float*)Bs;
    #pragma unroll
    for (int i = 0; i < 2; ++i) {
        int idx = tid + i * 256;
        int r = idx >> 2, q = (idx & 3) * 4;
        *(float4*)(x0s + r * 16 + q) =
            *(const float4*)(X + (size_t)(rowBase + r) * K_DIM + q);
        *(float4*)(w0s + r * 16 + q) =
            *(const float4*)(Wt + (size_t)(colBase + r) * K_DIM + q);
    }
    __syncthreads();

    const float TAU32 = (float)TAU_D;
    float wv[4][16];
    float bv[4];
    #pragma unroll
    for (int n = 0; n < 4; ++n) {
        int c = wc * 64 + n * 16 + lr;
        #pragma unroll
        for (int q = 0; q < 4; ++q)
            *(f32x4*)&wv[n][q * 4] = *(const f32x4*)(w0s + c * 16 + q * 4);
        bv[n] = bias[colBase + c];
    }

    #pragma unroll
    for (int m = 0; m < 4; ++m) {
        #pragma unroll
        for (int j = 0; j < 4; ++j) {
            const int r = wr * 64 + m * 16 + lq * 4 + j;
            float xv[16];
            #pragma unroll
            for (int q = 0; q < 4; ++q)
                *(f32x4*)&xv[q * 4] = *(const f32x4*)(x0s + r * 16 + q * 4);
            const size_t orow = (size_t)(rowBase + r) * N_DIM + colBase;
            #pragma unroll
            for (int n = 0; n < 4; ++n) {
                float y1 = 0.f, s2 = 0.f;
                #pragma unroll
                for (int k = 0; k < 16; ++k) {
                    float xk = xv[k];
                    float wk = wv[n][k];
                    float xx = xk * xk;
                    float ww = wk * wk;
                    y1 = fmaf(xk, wk, y1);
                    s2 = fmaf(xx, ww, s2);
                }
                float t = fabsf(y1) / sqrtf(s2 * 0.0625f);
                float v = (t < TAU32) ? 0.0f : (acc[m][n][j] + bv[n]);
                out[orow + wc * 64 + n * 16 + lr] = v;
            }
        }
    }
}

extern "C" void kernel_launch(void* const* d_in, const int* in_sizes, int n_in,
                              void* d_out, int out_size, void* d_ws, size_t ws_size,
                              hipStream_t stream) {
    const float* x    = (const float*)d_in[0];
    const float* W    = (const float*)d_in[1];
    const float* bias = (const float*)d_in[2];
    float* out = (float*)d_out;

    const size_t needA = (size_t)M_DIM * K_DIM * 2;   // 64 MB
    const size_t needB = (size_t)N_DIM * K_DIM * 2;   // 32 MB

    if (ws_size >= needA + needB) {
        unsigned short* xb = (unsigned short*)d_ws;
        unsigned short* wb = (unsigned short*)((char*)d_ws + needA);
        cvt_f32_to_bf16<<<2048, 256, 0, stream>>>(
            (const float4*)x, (uint2*)xb, (M_DIM * K_DIM) / 4);
        cvt_f32_to_bf16<<<2048, 256, 0, stream>>>(
            (const float4*)W, (uint2*)wb, (N_DIM * K_DIM) / 4);
        dim3 grid((M_DIM / 256) * (N_DIM / 256));     // 512 blocks, 1-D
        gemm_masked8<<<grid, 512, 0, stream>>>(xb, wb, x, W, bias, out);
    } else {
        dim3 grid(N_DIM / 128, M_DIM / 128);
        gemm_masked_fb<<<grid, 256, 0, stream>>>(x, W, bias, out);
    }
}

// Round 10
// 325.005 us; speedup vs baseline: 6.0424x; 1.0874x over previous
//
#include <hip/hip_runtime.h>
#include <cstdint>
#include <cstddef>

#define TAU_D 2.053748910631823
#define M_DIM 8192
#define N_DIM 4096
#define K_DIM 4096
#define NIT   32               // iterations; each covers 2 K-steps of BK=64

typedef float f32x4  __attribute__((ext_vector_type(4)));
typedef short bf16x8 __attribute__((ext_vector_type(8)));

typedef __attribute__((address_space(1))) void gvoid_t;
typedef __attribute__((address_space(3))) void lvoid_t;

__device__ __forceinline__ void gload_lds16(const void* g, void* l) {
    __builtin_amdgcn_global_load_lds((const gvoid_t*)g, (lvoid_t*)l, 16, 0, 0);
}

__device__ __forceinline__ unsigned int pack2bf(float lo, float hi) {
    unsigned int ul = __float_as_uint(lo);
    unsigned int uh = __float_as_uint(hi);
    ul = (ul + 0x7FFFu + ((ul >> 16) & 1u)) >> 16;
    uh = (uh + 0x7FFFu + ((uh >> 16) & 1u)) >> 16;
    return ul | (uh << 16);
}

// fp32 -> bf16 (RNE), vectorized: 16B in / 8B out per thread per iter.
__global__ void cvt_f32_to_bf16(const float4* __restrict__ in,
                                uint2* __restrict__ out, int n4) {
    int i = blockIdx.x * blockDim.x + threadIdx.x;
    const int stride = gridDim.x * blockDim.x;
    for (; i < n4; i += stride) {
        float4 a = in[i];
        uint2 o;
        o.x = pack2bf(a.x, a.y);
        o.y = pack2bf(a.z, a.w);
        out[i] = o;
    }
}

#define BARRIER() do { __builtin_amdgcn_s_barrier(); \
                       __builtin_amdgcn_sched_barrier(0); } while (0)

// ============================================================================
// m201-faithful 8-phase schedule. 256x256 tile, BK=64, 8 waves (2Mx4N),
// 512 thr, 2 LDS region-pairs R0/R1 (128KB), 1 block/CU.
// Iteration j computes K-step 2j from R0 (ph1-4) and 2j+1 from R1 (ph5-8);
// per K-step quadrant order (mq0,nq0),(mq0,nq1),(mq1,nq1),(mq1,nq0) with
// A-quadrant + B-nq0 held in regs (reads/phase: 12,4,8,0).
// Region-staggered staging (each target freed >=1 phase before write):
//   ph1: B(2j+1)->R1B   ph4: A(2j+2)->R0A   ph5: B(2j+2)->R0B   ph8: A(2j+3)->R1A
// Counted vmcnt(4) ONLY at ph4/ph8 (>=3-phase flight for every stage; queue
// never drains in-loop; vmcnt(0) only at last iteration's ph4).
// ds_read/staging/swizzle geometry identical to r6 (verified absmax 2.0).
// XCD cluster map verified r6 (FETCH 208MB). Epilogue bit-exact (r3-r9).
// ============================================================================
__global__ __launch_bounds__(512, 2) void gemm_masked8(
    const unsigned short* __restrict__ Ab,   // x bf16 [M][K]
    const unsigned short* __restrict__ Bb,   // W bf16 [N][K]
    const float* __restrict__ X,             // x fp32 (mask)
    const float* __restrict__ Wt,            // W fp32 (mask)
    const float* __restrict__ bias,
    float* __restrict__ out)
{
    __shared__ __align__(16) char lds[131072];   // R0A|R0B|R1A|R1B x 32KB

    const int tid  = threadIdx.x;
    const int wave = tid >> 6;
    const int lane = tid & 63;
    const int lr = lane & 15;
    const int lq = lane >> 4;
    const int wm = wave >> 2;    // 0..1 : row half (128 rows)
    const int wn = wave & 3;     // 0..3 : 64-col slice

    // Concurrency-aware XCD cluster map (verified r6).
    const int flat = blockIdx.x;
    const int xcd  = flat & 7;
    const int s    = flat >> 3;            // 0..63
    const int rnd  = s >> 5;               // 0..1
    const int jj   = s & 31;               // 0..31
    const int trow = rnd * 16 + ((xcd >> 2) << 3) + (jj >> 2);   // 0..31
    const int tcol = ((xcd & 3) << 2) + (jj & 3);                // 0..15
    const int rowBase = trow * 256;
    const int colBase = tcol * 256;

    f32x4 acc[8][4];
    #pragma unroll
    for (int i = 0; i < 8; ++i)
        #pragma unroll
        for (int n = 0; n < 4; ++n)
            acc[i][n] = (f32x4){0.f, 0.f, 0.f, 0.f};

    // ---- staging (r6-verified): linear LDS dest; global col pre-swizzled --
    // gload i: flat byte = region + i*8192 + tid*16 -> row = i*64 + (tid>>3),
    // phys 16B-slot = tid&7, logical slot fetched = (tid&7) ^ ((tid>>3)&7).
    const int srow  = tid >> 3;                       // 0..63
    const int sslot = (tid & 7) ^ (srow & 7);
    const unsigned short* aSrc =
        Ab + (size_t)(rowBase + srow) * K_DIM + sslot * 8;
    const unsigned short* bSrc =
        Bb + (size_t)(colBase + srow) * K_DIM + sslot * 8;

    // Region base offsets.
    const unsigned R0A = 0, R0B = 32768, R1A = 65536, R1B = 98304;

    auto stageA = [&](int kst, unsigned reg) {
        #pragma unroll
        for (int i = 0; i < 4; ++i)
            gload_lds16(aSrc + (size_t)i * 64 * K_DIM + kst * 64,
                        lds + reg + i * 8192 + wave * 1024);
    };
    auto stageB = [&](int kst, unsigned reg) {
        #pragma unroll
        for (int i = 0; i < 4; ++i)
            gload_lds16(bSrc + (size_t)i * 64 * K_DIM + kst * 64,
                        lds + reg + i * 8192 + wave * 1024);
    };

    // ---- ds_read offsets (r6-verified swizzle) ----
    // row = (whalf*stride + frag*16 + lr); byte = row*128 + ((ks*4+lq)^(lr&7))*16
    const unsigned kk0 = (unsigned)((lq) ^ (lr & 7)) * 16;
    const unsigned kk1 = (unsigned)((4 + lq) ^ (lr & 7)) * 16;
    const unsigned rowA = (unsigned)(wm * 128 + lr) * 128;   // + m*2048
    const unsigned rowB = (unsigned)(wn * 64 + lr) * 128;    // + nf*2048

    // ---- prologue: A(0),B(0)->R0; A(1)->R1A; B(1) staged at ph1 of j=0 ----
    stageA(0, R0A);
    stageB(0, R0B);
    stageA(1, R1A);
    asm volatile("s_waitcnt vmcnt(4)" ::: "memory");   // A0,B0 landed; A1 flying
    BARRIER();

    bf16x8 aF[4][2];     // held A quadrant (4 m-frags x 2 ks)
    bf16x8 bF0[2][2];    // B nq0 (held ph1..ph4 / ph5..ph8)
    bf16x8 bF1[2][2];    // B nq1

    for (int j = 0; j < NIT; ++j) {
        const int ka = 2 * j;            // K-step in R0
        const int kb = 2 * j + 1;        // K-step in R1
        const bool stg = (j + 1 < NIT);

        // ================= K-step ka from R0 =================
        // ---- ph1: quad(mq0,nq0); reads A0-3 + Bnq0; stage B(kb)->R1B ----
        #pragma unroll
        for (int m = 0; m < 4; ++m) {
            aF[m][0] = *(const bf16x8*)(lds + R0A + rowA + m * 2048 + kk0);
            aF[m][1] = *(const bf16x8*)(lds + R0A + rowA + m * 2048 + kk1);
        }
        #pragma unroll
        for (int n = 0; n < 2; ++n) {
            bF0[n][0] = *(const bf16x8*)(lds + R0B + rowB + n * 2048 + kk0);
            bF0[n][1] = *(const bf16x8*)(lds + R0B + rowB + n * 2048 + kk1);
        }
        stageB(kb, R1B);
        BARRIER();
        __builtin_amdgcn_s_setprio(1);
        #pragma unroll
        for (int m = 0; m < 4; ++m)
            #pragma unroll
            for (int n = 0; n < 2; ++n)
                #pragma unroll
                for (int ks = 0; ks < 2; ++ks)
                    acc[m][n] = __builtin_amdgcn_mfma_f32_16x16x32_bf16(
                        aF[m][ks], bF0[n][ks], acc[m][n], 0, 0, 0);
        __builtin_amdgcn_s_setprio(0);
        BARRIER();

        // ---- ph2: quad(mq0,nq1); reads Bnq1 ----
        #pragma unroll
        for (int n = 0; n < 2; ++n) {
            bF1[n][0] = *(const bf16x8*)(lds + R0B + rowB + (2 + n) * 2048 + kk0);
            bF1[n][1] = *(const bf16x8*)(lds + R0B + rowB + (2 + n) * 2048 + kk1);
        }
        BARRIER();
        __builtin_amdgcn_s_setprio(1);
        #pragma unroll
        for (int m = 0; m < 4; ++m)
            #pragma unroll
            for (int n = 0; n < 2; ++n)
                #pragma unroll
                for (int ks = 0; ks < 2; ++ks)
                    acc[m][2 + n] = __builtin_amdgcn_mfma_f32_16x16x32_bf16(
                        aF[m][ks], bF1[n][ks], acc[m][2 + n], 0, 0, 0);
        __builtin_amdgcn_s_setprio(0);
        BARRIER();

        // ---- ph3: quad(mq1,nq1); reads A4-7 ----
        #pragma unroll
        for (int m = 0; m < 4; ++m) {
            aF[m][0] = *(const bf16x8*)(lds + R0A + rowA + (4 + m) * 2048 + kk0);
            aF[m][1] = *(const bf16x8*)(lds + R0A + rowA + (4 + m) * 2048 + kk1);
        }
        BARRIER();
        __builtin_amdgcn_s_setprio(1);
        #pragma unroll
        for (int m = 0; m < 4; ++m)
            #pragma unroll
            for (int n = 0; n < 2; ++n)
                #pragma unroll
                for (int ks = 0; ks < 2; ++ks)
                    acc[4 + m][2 + n] = __builtin_amdgcn_mfma_f32_16x16x32_bf16(
                        aF[m][ks], bF1[n][ks], acc[4 + m][2 + n], 0, 0, 0);
        __builtin_amdgcn_s_setprio(0);
        BARRIER();

        // ---- ph4: quad(mq1,nq0); bF0 held; stage A(ka+2)->R0A ----
        if (stg) stageA(ka + 2, R0A);
        BARRIER();
        __builtin_amdgcn_s_setprio(1);
        #pragma unroll
        for (int m = 0; m < 4; ++m)
            #pragma unroll
            for (int n = 0; n < 2; ++n)
                #pragma unroll
                for (int ks = 0; ks < 2; ++ks)
                    acc[4 + m][n] = __builtin_amdgcn_mfma_f32_16x16x32_bf16(
                        aF[m][ks], bF0[n][ks], acc[4 + m][n], 0, 0, 0);
        __builtin_amdgcn_s_setprio(0);
        if (stg) {
            asm volatile("s_waitcnt vmcnt(4)" ::: "memory");  // B(kb) + older landed
        } else {
            asm volatile("s_waitcnt vmcnt(0)" ::: "memory");  // tail drain
        }
        BARRIER();

        // ================= K-step kb from R1 =================
        // ---- ph5: quad(mq0,nq0); stage B(ka+2)->R0B ----
        #pragma unroll
        for (int m = 0; m < 4; ++m) {
            aF[m][0] = *(const bf16x8*)(lds + R1A + rowA + m * 2048 + kk0);
            aF[m][1] = *(const bf16x8*)(lds + R1A + rowA + m * 2048 + kk1);
        }
        #pragma unroll
        for (int n = 0; n < 2; ++n) {
            bF0[n][0] = *(const bf16x8*)(lds + R1B + rowB + n * 2048 + kk0);
            bF0[n][1] = *(const bf16x8*)(lds + R1B + rowB + n * 2048 + kk1);
        }
        if (stg) stageB(ka + 2, R0B);
        BARRIER();
        __builtin_amdgcn_s_setprio(1);
        #pragma unroll
        for (int m = 0; m < 4; ++m)
            #pragma unroll
            for (int n = 0; n < 2; ++n)
                #pragma unroll
                for (int ks = 0; ks < 2; ++ks)
                    acc[m][n] = __builtin_amdgcn_mfma_f32_16x16x32_bf16(
                        aF[m][ks], bF0[n][ks], acc[m][n], 0, 0, 0);
        __builtin_amdgcn_s_setprio(0);
        BARRIER();

        // ---- ph6: quad(mq0,nq1) ----
        #pragma unroll
        for (int n = 0; n < 2; ++n) {
            bF1[n][0] = *(const bf16x8*)(lds + R1B + rowB + (2 + n) * 2048 + kk0);
            bF1[n][1] = *(const bf16x8*)(lds + R1B + rowB + (2 + n) * 2048 + kk1);
        }
        BARRIER();
        __builtin_amdgcn_s_setprio(1);
        #pragma unroll
        for (int m = 0; m < 4; ++m)
            #pragma unroll
            for (int n = 0; n < 2; ++n)
                #pragma unroll
                for (int ks = 0; ks < 2; ++ks)
                    acc[m][2 + n] = __builtin_amdgcn_mfma_f32_16x16x32_bf16(
                        aF[m][ks], bF1[n][ks], acc[m][2 + n], 0, 0, 0);
        __builtin_amdgcn_s_setprio(0);
        BARRIER();

        // ---- ph7: quad(mq1,nq1) ----
        #pragma unroll
        for (int m = 0; m < 4; ++m) {
            aF[m][0] = *(const bf16x8*)(lds + R1A + rowA + (4 + m) * 2048 + kk0);
            aF[m][1] = *(const bf16x8*)(lds + R1A + rowA + (4 + m) * 2048 + kk1);
        }
        BARRIER();
        __builtin_amdgcn_s_setprio(1);
        #pragma unroll
        for (int m = 0; m < 4; ++m)
            #pragma unroll
            for (int n = 0; n < 2; ++n)
                #pragma unroll
                for (int ks = 0; ks < 2; ++ks)
                    acc[4 + m][2 + n] = __builtin_amdgcn_mfma_f32_16x16x32_bf16(
                        aF[m][ks], bF1[n][ks], acc[4 + m][2 + n], 0, 0, 0);
        __builtin_amdgcn_s_setprio(0);
        BARRIER();

        // ---- ph8: quad(mq1,nq0); bF0 held; stage A(kb+2)->R1A ----
        if (stg) stageA(kb + 2, R1A);
        BARRIER();
        __builtin_amdgcn_s_setprio(1);
        #pragma unroll
        for (int m = 0; m < 4; ++m)
            #pragma unroll
            for (int n = 0; n < 2; ++n)
                #pragma unroll
                for (int ks = 0; ks < 2; ++ks)
                    acc[4 + m][n] = __builtin_amdgcn_mfma_f32_16x16x32_bf16(
                        aF[m][ks], bF0[n][ks], acc[4 + m][n], 0, 0, 0);
        __builtin_amdgcn_s_setprio(0);
        asm volatile("s_waitcnt vmcnt(4)" ::: "memory");  // A,B(ka+2) landed
        BARRIER();
    }

    // ---- epilogue: bit-exact fp32 mask + bias + store (verified r3-r9) ----
    __syncthreads();
    float* x0s = (float*)(lds);            // [256][16] f32, 16KB
    float* w0s = (float*)(lds + 16384);    // [256][16] f32
    #pragma unroll
    for (int i = 0; i < 2; ++i) {
        int idx = tid + i * 512;           // 1024 float4 slots
        int r = idx >> 2, qq = (idx & 3) << 2;
        *(f32x4*)(x0s + r * 16 + qq) =
            *(const f32x4*)(X + (size_t)(rowBase + r) * K_DIM + qq);
        *(f32x4*)(w0s + r * 16 + qq) =
            *(const f32x4*)(Wt + (size_t)(colBase + r) * K_DIM + qq);
    }
    __syncthreads();

    const float TAU32 = (float)TAU_D;

    // n in adjacent pairs: both 64B halves of each 128B output line stored
    // back-to-back (write-amplification fix, verified r6-r9).
    #pragma unroll
    for (int np = 0; np < 4; np += 2) {
        float wv[2][16];
        float bv[2];
        #pragma unroll
        for (int e = 0; e < 2; ++e) {
            const int c = wn * 64 + (np + e) * 16 + lr;
            #pragma unroll
            for (int q = 0; q < 4; ++q)
                *(f32x4*)&wv[e][q * 4] = *(const f32x4*)(w0s + c * 16 + q * 4);
            bv[e] = bias[colBase + c];
        }
        #pragma unroll
        for (int mi = 0; mi < 8; ++mi) {
            #pragma unroll
            for (int jr = 0; jr < 4; ++jr) {
                const int rw = wm * 128 + mi * 16 + lq * 4 + jr;
                float xv[16];
                #pragma unroll
                for (int q = 0; q < 4; ++q)
                    *(f32x4*)&xv[q * 4] = *(const f32x4*)(x0s + rw * 16 + q * 4);
                const size_t orow = (size_t)(rowBase + rw) * N_DIM + colBase;
                #pragma unroll
                for (int e = 0; e < 2; ++e) {
                    const int n = np + e;
                    // Replicate BLAS sgemm: single-acc fma chain, k ascending.
                    float y1 = 0.f, s2 = 0.f;
                    #pragma unroll
                    for (int k = 0; k < 16; ++k) {
                        float xk = xv[k], wk = wv[e][k];
                        float xx = xk * xk, ww = wk * wk;
                        y1 = fmaf(xk, wk, y1);
                        s2 = fmaf(xx, ww, s2);
                    }
                    float t = fabsf(y1) / sqrtf(s2 * 0.0625f);
                    float v = (t < TAU32) ? 0.0f : (acc[mi][n][jr] + bv[e]);
                    out[orow + wn * 64 + n * 16 + lr] = v;
                }
            }
        }
    }
}

// ============================================================================
// Fallback (no workspace): round-3 verified 128x128 kernel, reg-staged cvt.
// ============================================================================
__global__ __launch_bounds__(256, 2) void gemm_masked_fb(
    const float* __restrict__ X, const float* __restrict__ Wt,
    const float* __restrict__ bias, float* __restrict__ out)
{
    __shared__ __align__(16) unsigned short As[128 * 32];
    __shared__ __align__(16) unsigned short Bs[128 * 32];

    const int tid  = threadIdx.x;
    const int wave = tid >> 6;
    const int lane = tid & 63;
    const int rowBase = blockIdx.y * 128;
    const int colBase = blockIdx.x * 128;
    const int wr = wave >> 1;
    const int wc = wave & 1;
    const int lr = lane & 15;
    const int lq = lane >> 4;

    f32x4 acc[4][4];
    #pragma unroll
    for (int m = 0; m < 4; ++m)
        #pragma unroll
        for (int n = 0; n < 4; ++n)
            acc[m][n] = (f32x4){0.f, 0.f, 0.f, 0.f};

    const int srow = tid >> 2;
    const int scol = (tid & 3) * 8;
    const float* afp = X  + (size_t)(rowBase + srow) * K_DIM + scol;
    const float* bfp = Wt + (size_t)(colBase + srow) * K_DIM + scol;

    for (int kt = 0; kt < K_DIM; kt += 32) {
        #pragma unroll
        for (int issue = 0; issue < 2; ++issue) {
            const float* sa = afp + (size_t)issue * 64 * K_DIM;
            const float* sb = bfp + (size_t)issue * 64 * K_DIM;
            float4 a0 = *(const float4*)(sa);
            float4 a1 = *(const float4*)(sa + 4);
            float4 b0 = *(const float4*)(sb);
            float4 b1 = *(const float4*)(sb + 4);
            uint4 pa, pb;
            pa.x = pack2bf(a0.x, a0.y); pa.y = pack2bf(a0.z, a0.w);
            pa.z = pack2bf(a1.x, a1.y); pa.w = pack2bf(a1.z, a1.w);
            pb.x = pack2bf(b0.x, b0.y); pb.y = pack2bf(b0.z, b0.w);
            pb.z = pack2bf(b1.x, b1.y); pb.w = pack2bf(b1.z, b1.w);
            *(uint4*)((char*)As + issue * 4096 + tid * 16) = pa;
            *(uint4*)((char*)Bs + issue * 4096 + tid * 16) = pb;
        }
        afp += 32; bfp += 32;
        __syncthreads();

        bf16x8 af[4], bq[4];
        #pragma unroll
        for (int m = 0; m < 4; ++m)
            af[m] = *(const bf16x8*)(As + (wr * 64 + m * 16 + lr) * 32 + lq * 8);
        #pragma unroll
        for (int n = 0; n < 4; ++n)
            bq[n] = *(const bf16x8*)(Bs + (wc * 64 + n * 16 + lr) * 32 + lq * 8);
        #pragma unroll
        for (int m = 0; m < 4; ++m)
            #pragma unroll
            for (int n = 0; n < 4; ++n)
                acc[m][n] = __builtin_amdgcn_mfma_f32_16x16x32_bf16(
                    af[m], bq[n], acc[m][n], 0, 0, 0);
        __syncthreads();
    }

    float* x0s = (float*)As;
    float* w0s = (float*)Bs;
    #pragma unroll
    for (int i = 0; i < 2; ++i) {
        int idx = tid + i * 256;
        int r = idx >> 2, q = (idx & 3) * 4;
        *(float4*)(x0s + r * 16 + q) =
            *(const float4*)(X + (size_t)(rowBase + r) * K_DIM + q);
        *(float4*)(w0s + r * 16 + q) =
            *(const float4*)(Wt + (size_t)(colBase + r) * K_DIM + q);
    }
    __syncthreads();

    const float TAU32 = (float)TAU_D;
    float wv[4][16];
    float bv[4];
    #pragma unroll
    for (int n = 0; n < 4; ++n) {
        int c = wc * 64 + n * 16 + lr;
        #pragma unroll
        for (int q = 0; q < 4; ++q)
            *(f32x4*)&wv[n][q * 4] = *(const f32x4*)(w0s + c * 16 + q * 4);
        bv[n] = bias[colBase + c];
    }

    #pragma unroll
    for (int m = 0; m < 4; ++m) {
        #pragma unroll
        for (int j = 0; j < 4; ++j) {
            const int r = wr * 64 + m * 16 + lq * 4 + j;
            float xv[16];
            #pragma unroll
            for (int q = 0; q < 4; ++q)
                *(f32x4*)&xv[q * 4] = *(const f32x4*)(x0s + r * 16 + q * 4);
            const size_t orow = (size_t)(rowBase + r) * N_DIM + colBase;
            #pragma unroll
            for (int n = 0; n < 4; ++n) {
                float y1 = 0.f, s2 = 0.f;
                #pragma unroll
                for (int k = 0; k < 16; ++k) {
                    float xk = xv[k];
                    float wk = wv[n][k];
                    float xx = xk * xk;
                    float ww = wk * wk;
                    y1 = fmaf(xk, wk, y1);
                    s2 = fmaf(xx, ww, s2);
                }
                float t = fabsf(y1) / sqrtf(s2 * 0.0625f);
                float v = (t < TAU32) ? 0.0f : (acc[m][n][j] + bv[n]);
                out[orow + wc * 64 + n * 16 + lr] = v;
            }
        }
    }
}

extern "C" void kernel_launch(void* const* d_in, const int* in_sizes, int n_in,
                              void* d_out, int out_size, void* d_ws, size_t ws_size,
                              hipStream_t stream) {
    const float* x    = (const float*)d_in[0];
    const float* W    = (const float*)d_in[1];
    const float* bias = (const float*)d_in[2];
    float* out = (float*)d_out;

    const size_t needA = (size_t)M_DIM * K_DIM * 2;   // 64 MB
    const size_t needB = (size_t)N_DIM * K_DIM * 2;   // 32 MB

    if (ws_size >= needA + needB) {
        unsigned short* xb = (unsigned short*)d_ws;
        unsigned short* wb = (unsigned short*)((char*)d_ws + needA);
        cvt_f32_to_bf16<<<2048, 256, 0, stream>>>(
            (const float4*)x, (uint2*)xb, (M_DIM * K_DIM) / 4);
        cvt_f32_to_bf16<<<2048, 256, 0, stream>>>(
            (const float4*)W, (uint2*)wb, (N_DIM * K_DIM) / 4);
        dim3 grid((M_DIM / 256) * (N_DIM / 256));     // 512 blocks, 1-D
        gemm_masked8<<<grid, 512, 0, stream>>>(xb, wb, x, W, bias, out);
    } else {
        dim3 grid(N_DIM / 128, M_DIM / 128);
        gemm_masked_fb<<<grid, 256, 0, stream>>>(x, W, bias, out);
    }
}

// Round 11
// 315.870 us; speedup vs baseline: 6.2172x; 1.0289x over previous
//
#include <hip/hip_runtime.h>
#include <cstdint>
#include <cstddef>

#define TAU_D 2.053748910631823
#define M_DIM 8192
#define N_DIM 4096
#define K_DIM 4096
#define NIT   32               // iterations; each covers 2 K-steps of BK=64

typedef float f32x4  __attribute__((ext_vector_type(4)));
typedef short bf16x8 __attribute__((ext_vector_type(8)));

typedef __attribute__((address_space(1))) void gvoid_t;
typedef __attribute__((address_space(3))) void lvoid_t;

__device__ __forceinline__ void gload_lds16(const void* g, void* l) {
    __builtin_amdgcn_global_load_lds((const gvoid_t*)g, (lvoid_t*)l, 16, 0, 0);
}

__device__ __forceinline__ unsigned int pack2bf(float lo, float hi) {
    unsigned int ul = __float_as_uint(lo);
    unsigned int uh = __float_as_uint(hi);
    ul = (ul + 0x7FFFu + ((ul >> 16) & 1u)) >> 16;
    uh = (uh + 0x7FFFu + ((uh >> 16) & 1u)) >> 16;
    return ul | (uh << 16);
}

// fp32 -> bf16 (RNE), vectorized: 16B in / 8B out per thread per iter.
__global__ void cvt_f32_to_bf16(const float4* __restrict__ in,
                                uint2* __restrict__ out, int n4) {
    int i = blockIdx.x * blockDim.x + threadIdx.x;
    const int stride = gridDim.x * blockDim.x;
    for (; i < n4; i += stride) {
        float4 a = in[i];
        uint2 o;
        o.x = pack2bf(a.x, a.y);
        o.y = pack2bf(a.z, a.w);
        out[i] = o;
    }
}

// Raw barrier + COMPILER-ONLY memory fence (no sched_barrier(0): m141 showed
// full schedule pinning costs 1.7x; the empty clobber keeps memory ops
// phase-pinned for correctness while letting the scheduler interleave MFMA
// and fine-grained lgkmcnt waits across phases).
#define BARRIER() do { __builtin_amdgcn_s_barrier(); \
                       asm volatile("" ::: "memory"); } while (0)

// ============================================================================
// 8-phase schedule, m201-parity staging. 256x256 tile, BK=64, 8 waves (2Mx4N),
// 512 thr, 2 LDS region-pairs R0/R1 (128KB), 1 block/CU.
// Iteration j: K-step 2j from R0 (ph1-4), 2j+1 from R1 (ph5-8); quadrant
// order (mq0,nq0),(mq0,nq1),(mq1,nq1),(mq1,nq0); A-quad + B-nq0 held in regs.
// Staging: HALF-TILE (2 gloads) in EVERY phase, target freed >=1 phase prior:
//   ph1: A(2j+1)h0->R1A  ph2: A(2j+1)h1->R1A  ph3: B(2j+2)h0->R0B
//   ph4: B(2j+2)h1->R0B  ph5: A(2j+2)h0->R0A  ph6: A(2j+2)h1->R0A
//   ph7: B(2j+3)h0->R1B  ph8: B(2j+3)h1->R1B
// vmcnt(4) ONLY at ph4/ph8 (ledger: 12 outstanding, oldest 8 must land;
// 4 stay in flight across the barrier). vmcnt(0) only at last iter's ph4.
// ds_read/staging/swizzle geometry identical to r6/r10 (verified absmax 2.0).
// XCD cluster map verified r6 (FETCH 208MB). Epilogue bit-exact (r3-r10).
// ============================================================================
__global__ __launch_bounds__(512, 2) void gemm_masked8(
    const unsigned short* __restrict__ Ab,   // x bf16 [M][K]
    const unsigned short* __restrict__ Bb,   // W bf16 [N][K]
    const float* __restrict__ X,             // x fp32 (mask)
    const float* __restrict__ Wt,            // W fp32 (mask)
    const float* __restrict__ bias,
    float* __restrict__ out)
{
    __shared__ __align__(16) char lds[131072];   // R0A|R0B|R1A|R1B x 32KB

    const int tid  = threadIdx.x;
    const int wave = tid >> 6;
    const int lane = tid & 63;
    const int lr = lane & 15;
    const int lq = lane >> 4;
    const int wm = wave >> 2;    // 0..1 : row half (128 rows)
    const int wn = wave & 3;     // 0..3 : 64-col slice

    // Concurrency-aware XCD cluster map (verified r6).
    const int flat = blockIdx.x;
    const int xcd  = flat & 7;
    const int s    = flat >> 3;            // 0..63
    const int rnd  = s >> 5;               // 0..1
    const int jj   = s & 31;               // 0..31
    const int trow = rnd * 16 + ((xcd >> 2) << 3) + (jj >> 2);   // 0..31
    const int tcol = ((xcd & 3) << 2) + (jj & 3);                // 0..15
    const int rowBase = trow * 256;
    const int colBase = tcol * 256;

    f32x4 acc[8][4];
    #pragma unroll
    for (int i = 0; i < 8; ++i)
        #pragma unroll
        for (int n = 0; n < 4; ++n)
            acc[i][n] = (f32x4){0.f, 0.f, 0.f, 0.f};

    // ---- staging (r6-verified): linear LDS dest; global col pre-swizzled --
    const int srow  = tid >> 3;                       // 0..63
    const int sslot = (tid & 7) ^ (srow & 7);
    const unsigned short* aSrc =
        Ab + (size_t)(rowBase + srow) * K_DIM + sslot * 8;
    const unsigned short* bSrc =
        Bb + (size_t)(colBase + srow) * K_DIM + sslot * 8;

    const unsigned R0A = 0, R0B = 32768, R1A = 65536, R1B = 98304;

    // Half-tile stage: h in {0,1} -> gload i = 2h, 2h+1 (rows i*64..i*64+63).
    auto stageHalfA = [&](int kst, unsigned reg, int h) {
        #pragma unroll
        for (int i = 2 * h; i < 2 * h + 2; ++i)
            gload_lds16(aSrc + (size_t)i * 64 * K_DIM + kst * 64,
                        lds + reg + i * 8192 + wave * 1024);
    };
    auto stageHalfB = [&](int kst, unsigned reg, int h) {
        #pragma unroll
        for (int i = 2 * h; i < 2 * h + 2; ++i)
            gload_lds16(bSrc + (size_t)i * 64 * K_DIM + kst * 64,
                        lds + reg + i * 8192 + wave * 1024);
    };

    // ---- ds_read offsets (r6-verified swizzle) ----
    const unsigned kk0 = (unsigned)((lq) ^ (lr & 7)) * 16;
    const unsigned kk1 = (unsigned)((4 + lq) ^ (lr & 7)) * 16;
    const unsigned rowA = (unsigned)(wm * 128 + lr) * 128;   // + m*2048
    const unsigned rowB = (unsigned)(wn * 64 + lr) * 128;    // + nf*2048

    // ---- prologue: A(0),B(0)->R0 (8 loads); B(1)->R1B (4 loads) ----
    stageHalfA(0, R0A, 0); stageHalfA(0, R0A, 1);
    stageHalfB(0, R0B, 0); stageHalfB(0, R0B, 1);
    stageHalfB(1, R1B, 0); stageHalfB(1, R1B, 1);
    asm volatile("s_waitcnt vmcnt(4)" ::: "memory");   // A0,B0 landed; B1 flying
    BARRIER();

    bf16x8 aF[4][2];     // held A quadrant (4 m-frags x 2 ks)
    bf16x8 bF0[2][2];    // B nq0 (held across the K-step)
    bf16x8 bF1[2][2];    // B nq1

    for (int j = 0; j < NIT; ++j) {
        const int ka = 2 * j;            // K-step in R0
        const int kb = 2 * j + 1;        // K-step in R1
        const bool stg = (j + 1 < NIT);

        // ================= K-step ka from R0 =================
        // ---- ph1: quad(mq0,nq0); stage A(kb)h0 -> R1A ----
        #pragma unroll
        for (int m = 0; m < 4; ++m) {
            aF[m][0] = *(const bf16x8*)(lds + R0A + rowA + m * 2048 + kk0);
            aF[m][1] = *(const bf16x8*)(lds + R0A + rowA + m * 2048 + kk1);
        }
        #pragma unroll
        for (int n = 0; n < 2; ++n) {
            bF0[n][0] = *(const bf16x8*)(lds + R0B + rowB + n * 2048 + kk0);
            bF0[n][1] = *(const bf16x8*)(lds + R0B + rowB + n * 2048 + kk1);
        }
        stageHalfA(kb, R1A, 0);
        BARRIER();
        __builtin_amdgcn_s_setprio(1);
        #pragma unroll
        for (int m = 0; m < 4; ++m)
            #pragma unroll
            for (int n = 0; n < 2; ++n)
                #pragma unroll
                for (int ks = 0; ks < 2; ++ks)
                    acc[m][n] = __builtin_amdgcn_mfma_f32_16x16x32_bf16(
                        aF[m][ks], bF0[n][ks], acc[m][n], 0, 0, 0);
        __builtin_amdgcn_s_setprio(0);
        BARRIER();

        // ---- ph2: quad(mq0,nq1); stage A(kb)h1 -> R1A ----
        #pragma unroll
        for (int n = 0; n < 2; ++n) {
            bF1[n][0] = *(const bf16x8*)(lds + R0B + rowB + (2 + n) * 2048 + kk0);
            bF1[n][1] = *(const bf16x8*)(lds + R0B + rowB + (2 + n) * 2048 + kk1);
        }
        stageHalfA(kb, R1A, 1);
        BARRIER();
        __builtin_amdgcn_s_setprio(1);
        #pragma unroll
        for (int m = 0; m < 4; ++m)
            #pragma unroll
            for (int n = 0; n < 2; ++n)
                #pragma unroll
                for (int ks = 0; ks < 2; ++ks)
                    acc[m][2 + n] = __builtin_amdgcn_mfma_f32_16x16x32_bf16(
                        aF[m][ks], bF1[n][ks], acc[m][2 + n], 0, 0, 0);
        __builtin_amdgcn_s_setprio(0);
        BARRIER();

        // ---- ph3: quad(mq1,nq1); stage B(ka+2)h0 -> R0B ----
        #pragma unroll
        for (int m = 0; m < 4; ++m) {
            aF[m][0] = *(const bf16x8*)(lds + R0A + rowA + (4 + m) * 2048 + kk0);
            aF[m][1] = *(const bf16x8*)(lds + R0A + rowA + (4 + m) * 2048 + kk1);
        }
        if (stg) stageHalfB(ka + 2, R0B, 0);
        BARRIER();
        __builtin_amdgcn_s_setprio(1);
        #pragma unroll
        for (int m = 0; m < 4; ++m)
            #pragma unroll
            for (int n = 0; n < 2; ++n)
                #pragma unroll
                for (int ks = 0; ks < 2; ++ks)
                    acc[4 + m][2 + n] = __builtin_amdgcn_mfma_f32_16x16x32_bf16(
                        aF[m][ks], bF1[n][ks], acc[4 + m][2 + n], 0, 0, 0);
        __builtin_amdgcn_s_setprio(0);
        BARRIER();

        // ---- ph4: quad(mq1,nq0); stage B(ka+2)h1 -> R0B; vmcnt ----
        if (stg) stageHalfB(ka + 2, R0B, 1);
        __builtin_amdgcn_s_setprio(1);
        #pragma unroll
        for (int m = 0; m < 4; ++m)
            #pragma unroll
            for (int n = 0; n < 2; ++n)
                #pragma unroll
                for (int ks = 0; ks < 2; ++ks)
                    acc[4 + m][n] = __builtin_amdgcn_mfma_f32_16x16x32_bf16(
                        aF[m][ks], bF0[n][ks], acc[4 + m][n], 0, 0, 0);
        __builtin_amdgcn_s_setprio(0);
        if (stg) {
            asm volatile("s_waitcnt vmcnt(4)" ::: "memory");  // A(kb),B(kb) landed
        } else {
            asm volatile("s_waitcnt vmcnt(0)" ::: "memory");  // tail drain
        }
        BARRIER();

        // ================= K-step kb from R1 =================
        // ---- ph5: quad(mq0,nq0); stage A(ka+2)h0 -> R0A ----
        #pragma unroll
        for (int m = 0; m < 4; ++m) {
            aF[m][0] = *(const bf16x8*)(lds + R1A + rowA + m * 2048 + kk0);
            aF[m][1] = *(const bf16x8*)(lds + R1A + rowA + m * 2048 + kk1);
        }
        #pragma unroll
        for (int n = 0; n < 2; ++n) {
            bF0[n][0] = *(const bf16x8*)(lds + R1B + rowB + n * 2048 + kk0);
            bF0[n][1] = *(const bf16x8*)(lds + R1B + rowB + n * 2048 + kk1);
        }
        if (stg) stageHalfA(ka + 2, R0A, 0);
        BARRIER();
        __builtin_amdgcn_s_setprio(1);
        #pragma unroll
        for (int m = 0; m < 4; ++m)
            #pragma unroll
            for (int n = 0; n < 2; ++n)
                #pragma unroll
                for (int ks = 0; ks < 2; ++ks)
                    acc[m][n] = __builtin_amdgcn_mfma_f32_16x16x32_bf16(
                        aF[m][ks], bF0[n][ks], acc[m][n], 0, 0, 0);
        __builtin_amdgcn_s_setprio(0);
        BARRIER();

        // ---- ph6: quad(mq0,nq1); stage A(ka+2)h1 -> R0A ----
        #pragma unroll
        for (int n = 0; n < 2; ++n) {
            bF1[n][0] = *(const bf16x8*)(lds + R1B + rowB + (2 + n) * 2048 + kk0);
            bF1[n][1] = *(const bf16x8*)(lds + R1B + rowB + (2 + n) * 2048 + kk1);
        }
        if (stg) stageHalfA(ka + 2, R0A, 1);
        BARRIER();
        __builtin_amdgcn_s_setprio(1);
        #pragma unroll
        for (int m = 0; m < 4; ++m)
            #pragma unroll
            for (int n = 0; n < 2; ++n)
                #pragma unroll
                for (int ks = 0; ks < 2; ++ks)
                    acc[m][2 + n] = __builtin_amdgcn_mfma_f32_16x16x32_bf16(
                        aF[m][ks], bF1[n][ks], acc[m][2 + n], 0, 0, 0);
        __builtin_amdgcn_s_setprio(0);
        BARRIER();

        // ---- ph7: quad(mq1,nq1); stage B(kb+2)h0 -> R1B ----
        #pragma unroll
        for (int m = 0; m < 4; ++m) {
            aF[m][0] = *(const bf16x8*)(lds + R1A + rowA + (4 + m) * 2048 + kk0);
            aF[m][1] = *(const bf16x8*)(lds + R1A + rowA + (4 + m) * 2048 + kk1);
        }
        if (stg) stageHalfB(kb + 2, R1B, 0);
        BARRIER();
        __builtin_amdgcn_s_setprio(1);
        #pragma unroll
        for (int m = 0; m < 4; ++m)
            #pragma unroll
            for (int n = 0; n < 2; ++n)
                #pragma unroll
                for (int ks = 0; ks < 2; ++ks)
                    acc[4 + m][2 + n] = __builtin_amdgcn_mfma_f32_16x16x32_bf16(
                        aF[m][ks], bF1[n][ks], acc[4 + m][2 + n], 0, 0, 0);
        __builtin_amdgcn_s_setprio(0);
        BARRIER();

        // ---- ph8: quad(mq1,nq0); stage B(kb+2)h1 -> R1B; vmcnt(4) ----
        if (stg) stageHalfB(kb + 2, R1B, 1);
        __builtin_amdgcn_s_setprio(1);
        #pragma unroll
        for (int m = 0; m < 4; ++m)
            #pragma unroll
            for (int n = 0; n < 2; ++n)
                #pragma unroll
                for (int ks = 0; ks < 2; ++ks)
                    acc[4 + m][n] = __builtin_amdgcn_mfma_f32_16x16x32_bf16(
                        aF[m][ks], bF0[n][ks], acc[4 + m][n], 0, 0, 0);
        __builtin_amdgcn_s_setprio(0);
        if (stg)
            asm volatile("s_waitcnt vmcnt(4)" ::: "memory");  // A,B(ka+2) landed
        BARRIER();
    }

    // ---- epilogue: bit-exact fp32 mask + bias + store (verified r3-r10) ---
    __syncthreads();
    float* x0s = (float*)(lds);            // [256][16] f32, 16KB
    float* w0s = (float*)(lds + 16384);    // [256][16] f32
    #pragma unroll
    for (int i = 0; i < 2; ++i) {
        int idx = tid + i * 512;           // 1024 float4 slots
        int r = idx >> 2, qq = (idx & 3) << 2;
        *(f32x4*)(x0s + r * 16 + qq) =
            *(const f32x4*)(X + (size_t)(rowBase + r) * K_DIM + qq);
        *(f32x4*)(w0s + r * 16 + qq) =
            *(const f32x4*)(Wt + (size_t)(colBase + r) * K_DIM + qq);
    }
    __syncthreads();

    const float TAU32 = (float)TAU_D;

    // n in adjacent pairs: both 64B halves of each 128B output line stored
    // back-to-back (write-amplification fix, verified r6-r10).
    #pragma unroll
    for (int np = 0; np < 4; np += 2) {
        float wv[2][16];
        float bv[2];
        #pragma unroll
        for (int e = 0; e < 2; ++e) {
            const int c = wn * 64 + (np + e) * 16 + lr;
            #pragma unroll
            for (int q = 0; q < 4; ++q)
                *(f32x4*)&wv[e][q * 4] = *(const f32x4*)(w0s + c * 16 + q * 4);
            bv[e] = bias[colBase + c];
        }
        #pragma unroll
        for (int mi = 0; mi < 8; ++mi) {
            #pragma unroll
            for (int jr = 0; jr < 4; ++jr) {
                const int rw = wm * 128 + mi * 16 + lq * 4 + jr;
                float xv[16];
                #pragma unroll
                for (int q = 0; q < 4; ++q)
                    *(f32x4*)&xv[q * 4] = *(const f32x4*)(x0s + rw * 16 + q * 4);
                const size_t orow = (size_t)(rowBase + rw) * N_DIM + colBase;
                #pragma unroll
                for (int e = 0; e < 2; ++e) {
                    const int n = np + e;
                    // Replicate BLAS sgemm: single-acc fma chain, k ascending.
                    float y1 = 0.f, s2 = 0.f;
                    #pragma unroll
                    for (int k = 0; k < 16; ++k) {
                        float xk = xv[k], wk = wv[e][k];
                        float xx = xk * xk, ww = wk * wk;
                        y1 = fmaf(xk, wk, y1);
                        s2 = fmaf(xx, ww, s2);
                    }
                    float t = fabsf(y1) / sqrtf(s2 * 0.0625f);
                    float v = (t < TAU32) ? 0.0f : (acc[mi][n][jr] + bv[e]);
                    out[orow + wn * 64 + n * 16 + lr] = v;
                }
            }
        }
    }
}

// ============================================================================
// Fallback (no workspace): round-3 verified 128x128 kernel, reg-staged cvt.
// ============================================================================
__global__ __launch_bounds__(256, 2) void gemm_masked_fb(
    const float* __restrict__ X, const float* __restrict__ Wt,
    const float* __restrict__ bias, float* __restrict__ out)
{
    __shared__ __align__(16) unsigned short As[128 * 32];
    __shared__ __align__(16) unsigned short Bs[128 * 32];

    const int tid  = threadIdx.x;
    const int wave = tid >> 6;
    const int lane = tid & 63;
    const int rowBase = blockIdx.y * 128;
    const int colBase = blockIdx.x * 128;
    const int wr = wave >> 1;
    const int wc = wave & 1;
    const int lr = lane & 15;
    const int lq = lane >> 4;

    f32x4 acc[4][4];
    #pragma unroll
    for (int m = 0; m < 4; ++m)
        #pragma unroll
        for (int n = 0; n < 4; ++n)
            acc[m][n] = (f32x4){0.f, 0.f, 0.f, 0.f};

    const int srow = tid >> 2;
    const int scol = (tid & 3) * 8;
    const float* afp = X  + (size_t)(rowBase + srow) * K_DIM + scol;
    const float* bfp = Wt + (size_t)(colBase + srow) * K_DIM + scol;

    for (int kt = 0; kt < K_DIM; kt += 32) {
        #pragma unroll
        for (int issue = 0; issue < 2; ++issue) {
            const float* sa = afp + (size_t)issue * 64 * K_DIM;
            const float* sb = bfp + (size_t)issue * 64 * K_DIM;
            float4 a0 = *(const float4*)(sa);
            float4 a1 = *(const float4*)(sa + 4);
            float4 b0 = *(const float4*)(sb);
            float4 b1 = *(const float4*)(sb + 4);
            uint4 pa, pb;
            pa.x = pack2bf(a0.x, a0.y); pa.y = pack2bf(a0.z, a0.w);
            pa.z = pack2bf(a1.x, a1.y); pa.w = pack2bf(a1.z, a1.w);
            pb.x = pack2bf(b0.x, b0.y); pb.y = pack2bf(b0.z, b0.w);
            pb.z = pack2bf(b1.x, b1.y); pb.w = pack2bf(b1.z, b1.w);
            *(uint4*)((char*)As + issue * 4096 + tid * 16) = pa;
            *(uint4*)((char*)Bs + issue * 4096 + tid * 16) = pb;
        }
        afp += 32; bfp += 32;
        __syncthreads();

        bf16x8 af[4], bq[4];
        #pragma unroll
        for (int m = 0; m < 4; ++m)
            af[m] = *(const bf16x8*)(As + (wr * 64 + m * 16 + lr) * 32 + lq * 8);
        #pragma unroll
        for (int n = 0; n < 4; ++n)
            bq[n] = *(const bf16x8*)(Bs + (wc * 64 + n * 16 + lr) * 32 + lq * 8);
        #pragma unroll
        for (int m = 0; m < 4; ++m)
            #pragma unroll
            for (int n = 0; n < 4; ++n)
                acc[m][n] = __builtin_amdgcn_mfma_f32_16x16x32_bf16(
                    af[m], bq[n], acc[m][n], 0, 0, 0);
        __syncthreads();
    }

    float* x0s = (float*)As;
    float* w0s = (float*)Bs;
    #pragma unroll
    for (int i = 0; i < 2; ++i) {
        int idx = tid + i * 256;
        int r = idx >> 2, q = (idx & 3) * 4;
        *(float4*)(x0s + r * 16 + q) =
            *(const float4*)(X + (size_t)(rowBase + r) * K_DIM + q);
        *(float4*)(w0s + r * 16 + q) =
            *(const float4*)(Wt + (size_t)(colBase + r) * K_DIM + q);
    }
    __syncthreads();

    const float TAU32 = (float)TAU_D;
    float wv[4][16];
    float bv[4];
    #pragma unroll
    for (int n = 0; n < 4; ++n) {
        int c = wc * 64 + n * 16 + lr;
        #pragma unroll
        for (int q = 0; q < 4; ++q)
            *(f32x4*)&wv[n][q * 4] = *(const f32x4*)(w0s + c * 16 + q * 4);
        bv[n] = bias[colBase + c];
    }

    #pragma unroll
    for (int m = 0; m < 4; ++m) {
        #pragma unroll
        for (int j = 0; j < 4; ++j) {
            const int r = wr * 64 + m * 16 + lq * 4 + j;
            float xv[16];
            #pragma unroll
            for (int q = 0; q < 4; ++q)
                *(f32x4*)&xv[q * 4] = *(const f32x4*)(x0s + r * 16 + q * 4);
            const size_t orow = (size_t)(rowBase + r) * N_DIM + colBase;
            #pragma unroll
            for (int n = 0; n < 4; ++n) {
                float y1 = 0.f, s2 = 0.f;
                #pragma unroll
                for (int k = 0; k < 16; ++k) {
                    float xk = xv[k];
                    float wk = wv[n][k];
                    float xx = xk * xk;
                    float ww = wk * wk;
                    y1 = fmaf(xk, wk, y1);
                    s2 = fmaf(xx, ww, s2);
                }
                float t = fabsf(y1) / sqrtf(s2 * 0.0625f);
                float v = (t < TAU32) ? 0.0f : (acc[m][n][j] + bv[n]);
                out[orow + wc * 64 + n * 16 + lr] = v;
            }
        }
    }
}

extern "C" void kernel_launch(void* const* d_in, const int* in_sizes, int n_in,
                              void* d_out, int out_size, void* d_ws, size_t ws_size,
                              hipStream_t stream) {
    const float* x    = (const float*)d_in[0];
    const float* W    = (const float*)d_in[1];
    const float* bias = (const float*)d_in[2];
    float* out = (float*)d_out;

    const size_t needA = (size_t)M_DIM * K_DIM * 2;   // 64 MB
    const size_t needB = (size_t)N_DIM * K_DIM * 2;   // 32 MB

    if (ws_size >= needA + needB) {
        unsigned short* xb = (unsigned short*)d_ws;
        unsigned short* wb = (unsigned short*)((char*)d_ws + needA);
        cvt_f32_to_bf16<<<2048, 256, 0, stream>>>(
            (const float4*)x, (uint2*)xb, (M_DIM * K_DIM) / 4);
        cvt_f32_to_bf16<<<2048, 256, 0, stream>>>(
            (const float4*)W, (uint2*)wb, (N_DIM * K_DIM) / 4);
        dim3 grid((M_DIM / 256) * (N_DIM / 256));     // 512 blocks, 1-D
        gemm_masked8<<<grid, 512, 0, stream>>>(xb, wb, x, W, bias, out);
    } else {
        dim3 grid(N_DIM / 128, M_DIM / 128);
        gemm_masked_fb<<<grid, 256, 0, stream>>>(x, W, bias, out);
    }
}